// Round 8
// baseline (638.419 us; speedup 1.0000x reference)
//
#include <hip/hip_runtime.h>

#define N_N 100000
#define N_E 1600000
#define E_T (N_E + N_N)

#define NBKT 196          // ceil(N_N / 512)
#define BKT_CAP 12288     // mean 8704, sigma ~93 -> 38 sigma headroom

typedef long long ll;
typedef unsigned int uint;
typedef unsigned short ushort;

__device__ __forceinline__ float lrelu(float v){ return v > 0.f ? v : 0.2f*v; }

__device__ __forceinline__ ushort f2bf(float f){
  uint u = __float_as_uint(f);
  uint r = (u + 0x7FFF + ((u >> 16) & 1)) >> 16;
  return (ushort)r;
}
__device__ __forceinline__ float bflo(uint p){ return __uint_as_float(p << 16); }
__device__ __forceinline__ float bfhi(uint p){ return __uint_as_float(p & 0xFFFF0000u); }

// Detect int64 vs int32 delivery of edge_index.
__global__ void k_detect(const int* __restrict__ ei32, int* __restrict__ mode) {
  int m = 1;
  for (int i = 1; i < 16; i += 2) if (ei32[i] != 0) m = 0;
  *mode = m;
}

__device__ __forceinline__ void load_edge(const void* eiv, int mode, int e, int& s, int& d) {
  if (e < N_E) {
    if (mode) {
      const ll* p = (const ll*)eiv;
      s = (int)p[e]; d = (int)p[N_E + e];
    } else {
      const int* p = (const int*)eiv;
      s = p[e]; d = p[N_E + e];
    }
  } else { s = d = e - N_E; }
}

__global__ void k_zeroi(int* __restrict__ p, int n) {
  for (int i = blockIdx.x*blockDim.x + threadIdx.x; i < n; i += gridDim.x*blockDim.x)
    p[i] = 0;
}

// ---------------- bucketed CSR build ----------------------------------------
// phase 1: append packed (dlow<<17 | s) into per-bucket staging regions.
// only 196 append tails -> consecutive stores share L2 lines (no 32x write amp).
__global__ __launch_bounds__(256) void k_bucket(const void* __restrict__ eiv,
    const int* __restrict__ modep, int* __restrict__ bktpos, uint* __restrict__ stage)
{
  int e = blockIdx.x*256 + threadIdx.x;
  if (e >= E_T) return;
  int m = *modep, s, d;
  load_edge(eiv, m, e, s, d);
  int b = d >> 9;
  int dlow = d & 511;
  int pos = atomicAdd(&bktpos[b*16], 1);   // padded counters: 64B apart
  if (pos < BKT_CAP) stage[(size_t)b*BKT_CAP + pos] = ((uint)dlow << 17) | (uint)s;
}

// bucket base = exclusive prefix over bucket counts; also rptr[N] = E_T.
__global__ void k_bktscan(const int* __restrict__ bktpos, int* __restrict__ bktbase,
    int* __restrict__ rptrN)
{
  if (threadIdx.x == 0) {
    int run = 0;
    for (int b = 0; b < NBKT; ++b) { bktbase[b] = run; run += bktpos[b*16]; }
    *rptrN = run;
  }
}

// phase 2: one block per bucket. LDS hist over the bucket's 512 nodes,
// LDS ping-pong scan -> rptr, LDS-atomic ranks -> csr_col (~35KB write window).
__global__ __launch_bounds__(256) void k_bucket2(const int* __restrict__ bktpos,
    const int* __restrict__ bktbase, const uint* __restrict__ stage,
    int* __restrict__ csr_col, int* __restrict__ rptr)
{
  __shared__ int cntA[512], pA[512], pB[512], lpos[512];
  int b = blockIdx.x, t = threadIdx.x;
  int cnt = bktpos[b*16];
  if (cnt > BKT_CAP) cnt = BKT_CAP;
  int base = bktbase[b];
  const uint* st = stage + (size_t)b*BKT_CAP;
  for (int i = t; i < 512; i += 256) { cntA[i] = 0; lpos[i] = 0; }
  __syncthreads();
  for (int i = t; i < cnt; i += 256) atomicAdd(&cntA[st[i] >> 17], 1);
  __syncthreads();
  int* src = pA; int* dst = pB;
  for (int i = t; i < 512; i += 256) pA[i] = cntA[i];
  __syncthreads();
  for (int off = 1; off < 512; off <<= 1) {
    for (int i = t; i < 512; i += 256) {
      int v = src[i]; if (i >= off) v += src[i - off]; dst[i] = v;
    }
    __syncthreads();
    int* tmp = src; src = dst; dst = tmp;
  }
  // src = inclusive prefix; exclusive = src[i] - cntA[i]
  int nb0 = b*512;
  for (int i = t; i < 512; i += 256) {
    int node = nb0 + i;
    if (node < N_N) rptr[node] = base + src[i] - cntA[i];
  }
  __syncthreads();
  for (int i = t; i < cnt; i += 256) {
    uint pk = st[i];
    int dlow = (int)(pk >> 17), s = (int)(pk & 0x1FFFFu);
    int r = atomicAdd(&lpos[dlow], 1);
    csr_col[base + (src[dlow] - cntA[dlow]) + r] = s;
  }
}

// ---------------- proj: h0 = relu(x @ Wp + bp) ------------------------------
__global__ __launch_bounds__(256) void k_proj(const float* __restrict__ x,
    const float* __restrict__ Wp, const float* __restrict__ bp,
    float* __restrict__ h0)
{
  __shared__ float wl[64*128];
  __shared__ float xr[32*68];
  const int t = threadIdx.x;
  const int r0g = blockIdx.x * 32;
  for (int i = t; i < 64*128; i += 256) wl[i] = Wp[i];
  for (int i = t; i < 32*64; i += 256) {
    int r = i >> 6, k = i & 63;
    xr[r*68 + k] = x[(size_t)(r0g + r)*64 + k];
  }
  __syncthreads();
  const int tx = t & 31, ty = t >> 5;
  const int c0 = tx*4, r0 = ty*4;
  float acc[4][4] = {};
  for (int k = 0; k < 64; ++k) {
    float4 wv = *(const float4*)&wl[k*128 + c0];
    float x0 = xr[(r0+0)*68+k], x1 = xr[(r0+1)*68+k];
    float x2 = xr[(r0+2)*68+k], x3 = xr[(r0+3)*68+k];
    acc[0][0] += x0*wv.x; acc[0][1] += x0*wv.y; acc[0][2] += x0*wv.z; acc[0][3] += x0*wv.w;
    acc[1][0] += x1*wv.x; acc[1][1] += x1*wv.y; acc[1][2] += x1*wv.z; acc[1][3] += x1*wv.w;
    acc[2][0] += x2*wv.x; acc[2][1] += x2*wv.y; acc[2][2] += x2*wv.z; acc[2][3] += x2*wv.w;
    acc[3][0] += x3*wv.x; acc[3][1] += x3*wv.y; acc[3][2] += x3*wv.z; acc[3][3] += x3*wv.w;
  }
  float4 bb = *(const float4*)&bp[c0];
  for (int i = 0; i < 4; ++i) {
    int r = r0g + r0 + i;
    float4 o;
    o.x = fmaxf(acc[i][0] + bb.x, 0.f);
    o.y = fmaxf(acc[i][1] + bb.y, 0.f);
    o.z = fmaxf(acc[i][2] + bb.z, 0.f);
    o.w = fmaxf(acc[i][3] + bb.w, 0.f);
    *(float4*)&h0[(size_t)r*128 + c0] = o;
  }
}

// ------- layer-1 GEMM: H1(bf16) = h0 @ W1, fused alpha dots -----------------
__global__ __launch_bounds__(256) void k_gat_gemm128(const float* __restrict__ A,
    const float* __restrict__ W, const float* __restrict__ avs,
    const float* __restrict__ avd, ushort* __restrict__ Hb,
    float* __restrict__ as_o, float* __restrict__ ad_o)
{
  __shared__ float wl[64*128];
  __shared__ float xr[32*68];
  const int t = threadIdx.x;
  const int r0g = blockIdx.x * 32;
  const int tx = t & 31, ty = t >> 5;
  const int c0 = tx*4, r0 = ty*4;
  float acc[4][4] = {};
  for (int kc = 0; kc < 2; ++kc) {
    const int k0 = kc*64;
    if (kc) __syncthreads();
    for (int i = t; i < 64*128; i += 256) wl[i] = W[k0*128 + i];
    for (int i = t; i < 32*64; i += 256) {
      int r = i >> 6, k = i & 63;
      xr[r*68 + k] = A[(size_t)(r0g + r)*128 + k0 + k];
    }
    __syncthreads();
    for (int k = 0; k < 64; ++k) {
      float4 wv = *(const float4*)&wl[k*128 + c0];
      float x0 = xr[(r0+0)*68+k], x1 = xr[(r0+1)*68+k];
      float x2 = xr[(r0+2)*68+k], x3 = xr[(r0+3)*68+k];
      acc[0][0] += x0*wv.x; acc[0][1] += x0*wv.y; acc[0][2] += x0*wv.z; acc[0][3] += x0*wv.w;
      acc[1][0] += x1*wv.x; acc[1][1] += x1*wv.y; acc[1][2] += x1*wv.z; acc[1][3] += x1*wv.w;
      acc[2][0] += x2*wv.x; acc[2][1] += x2*wv.y; acc[2][2] += x2*wv.z; acc[2][3] += x2*wv.w;
      acc[3][0] += x3*wv.x; acc[3][1] += x3*wv.y; acc[3][2] += x3*wv.z; acc[3][3] += x3*wv.w;
    }
  }
  for (int i = 0; i < 4; ++i) {
    int r = r0g + r0 + i;
    uint p0 = (uint)f2bf(acc[i][0]) | ((uint)f2bf(acc[i][1]) << 16);
    uint p1 = (uint)f2bf(acc[i][2]) | ((uint)f2bf(acc[i][3]) << 16);
    *(uint2*)&Hb[(size_t)r*128 + c0] = make_uint2(p0, p1);
  }
  float4 sa = *(const float4*)&avs[c0];
  float4 da = *(const float4*)&avd[c0];
  for (int i = 0; i < 4; ++i) {
    float vs = acc[i][0]*sa.x + acc[i][1]*sa.y + acc[i][2]*sa.z + acc[i][3]*sa.w;
    float vd = acc[i][0]*da.x + acc[i][1]*da.y + acc[i][2]*da.z + acc[i][3]*da.w;
    vs += __shfl_xor(vs, 1); vs += __shfl_xor(vs, 2); vs += __shfl_xor(vs, 4);
    vd += __shfl_xor(vd, 1); vd += __shfl_xor(vd, 2); vd += __shfl_xor(vd, 4);
    if ((tx & 7) == 0) {
      int r = r0g + r0 + i;
      as_o[r*4 + (tx >> 3)] = vs;
      ad_o[r*4 + (tx >> 3)] = vd;
    }
  }
}

// ------------- fold W2 with att2 vectors ------------------------------------
__global__ void k_fold2(const float* __restrict__ W2,
    const float* __restrict__ att_s2, const float* __restrict__ att_d2,
    float* __restrict__ vs2, float* __restrict__ vd2)
{
  int t = threadIdx.x;            // 512 threads: k = t&127, h = t>>7
  int k = t & 127, hh = t >> 7;
  float accs = 0.f, accd = 0.f;
  for (int c = 0; c < 128; ++c) {
    float w = W2[(size_t)k*512 + hh*128 + c];
    accs += w * att_s2[hh*128 + c];
    accd += w * att_d2[hh*128 + c];
  }
  vs2[hh*128 + k] = accs;
  vd2[hh*128 + k] = accd;
}

// ------- fused layer-1 aggregate (wave per dst) + BN/ELU + layer-2 alpha ----
__global__ __launch_bounds__(256) void k_agg1(const int* __restrict__ rptr,
    const int* __restrict__ csr_col, const ushort* __restrict__ Hb,
    const float* __restrict__ as1, const float* __restrict__ ad1,
    const float* __restrict__ b1, const float* __restrict__ gamma,
    const float* __restrict__ beta, const float* __restrict__ vs2,
    const float* __restrict__ vd2, ushort* __restrict__ a1b,
    float* __restrict__ as2, float* __restrict__ ad2)
{
  int wid = threadIdx.x >> 6, l = threadIdx.x & 63;
  int n = blockIdx.x*4 + wid;
  if (n >= N_N) return;
  int jm = l & 15, hm = l >> 4;
  float adm = ad1[n*4 + hm];
  int beg = rptr[n], end = rptr[n+1];
  float accx = 0.f, accy = 0.f, den = 0.f;
  for (int e0 = beg; e0 < end; e0 += 16) {
    int ne = end - e0; if (ne > 16) ne = 16;
    int sM = 0; float wM = 0.f;
    if (jm < ne) {
      sM = csr_col[e0 + jm];
      wM = __expf(lrelu(as1[sM*4 + hm] + adm));
    }
    den += wM;
    for (int j = 0; j < ne; ++j) {
      int s = __shfl(sM, j);
      float w = __shfl(wM, (l & 48) + j);
      uint hv = *(const uint*)&Hb[(size_t)s*128 + 2*l];
      accx += w * bflo(hv);
      accy += w * bfhi(hv);
    }
  }
  den += __shfl_xor(den, 1); den += __shfl_xor(den, 2);
  den += __shfl_xor(den, 4); den += __shfl_xor(den, 8);
  float inv = 1.f / den;
  int c = 2*l;
  const float sc = 0.9999950000374997f;   // 1/sqrt(1+1e-5)
  float vx = (accx*inv + b1[c])   * (gamma[c]   * sc) + beta[c];
  float vy = (accy*inv + b1[c+1]) * (gamma[c+1] * sc) + beta[c+1];
  vx = vx > 0.f ? vx : __expf(vx) - 1.f;
  vy = vy > 0.f ? vy : __expf(vy) - 1.f;
  *(uint*)&a1b[(size_t)n*128 + c] = (uint)f2bf(vx) | ((uint)f2bf(vy) << 16);
  #pragma unroll
  for (int hh = 0; hh < 4; ++hh) {
    float2 wsv = *(const float2*)&vs2[hh*128 + c];
    float2 wdv = *(const float2*)&vd2[hh*128 + c];
    float ps = wsv.x*vx + wsv.y*vy;
    float pd = wdv.x*vx + wdv.y*vy;
    ps += __shfl_xor(ps, 1); ps += __shfl_xor(ps, 2); ps += __shfl_xor(ps, 4);
    ps += __shfl_xor(ps, 8); ps += __shfl_xor(ps, 16); ps += __shfl_xor(ps, 32);
    pd += __shfl_xor(pd, 1); pd += __shfl_xor(pd, 2); pd += __shfl_xor(pd, 4);
    pd += __shfl_xor(pd, 8); pd += __shfl_xor(pd, 16); pd += __shfl_xor(pd, 32);
    if (l == 0) { as2[n*4 + hh] = ps; ad2[n*4 + hh] = pd; }
  }
}

// ------- layer-2 tail: u[h,k] = sum_d sum_{s in N(d)} alpha*a1[s,k] ---------
__global__ __launch_bounds__(512) void k_tail2(const int* __restrict__ rptr,
    const int* __restrict__ csr_col, const ushort* __restrict__ a1b,
    const float* __restrict__ as2, const float* __restrict__ ad2,
    float* __restrict__ u)
{
  int wid = threadIdx.x >> 6, l = threadIdx.x & 63;
  int jm = l & 15, hm = l >> 4;
  int c0 = jm * 8;
  float acc[8] = {};
  for (int n = blockIdx.x*8 + wid; n < N_N; n += gridDim.x*8) {
    int beg = rptr[n], end = rptr[n+1];
    float adm = ad2[n*4 + hm];
    float accn[8] = {};
    float dsum = 0.f;
    for (int e0 = beg; e0 < end; e0 += 16) {
      int ne = end - e0; if (ne > 16) ne = 16;
      int sM = 0; float wM = 0.f;
      if (jm < ne) {
        sM = csr_col[e0 + jm];
        wM = __expf(lrelu(as2[sM*4 + hm] + adm));
      }
      dsum += wM;
      #pragma unroll 4
      for (int j = 0; j < ne; ++j) {
        int s = __shfl(sM, j);
        float w = __shfl(wM, (l & 48) + j);
        uint4 hv = *(const uint4*)&a1b[(size_t)s*128 + c0];
        accn[0] += w * bflo(hv.x); accn[1] += w * bfhi(hv.x);
        accn[2] += w * bflo(hv.y); accn[3] += w * bfhi(hv.y);
        accn[4] += w * bflo(hv.z); accn[5] += w * bfhi(hv.z);
        accn[6] += w * bflo(hv.w); accn[7] += w * bfhi(hv.w);
      }
    }
    dsum += __shfl_xor(dsum, 1); dsum += __shfl_xor(dsum, 2);
    dsum += __shfl_xor(dsum, 4); dsum += __shfl_xor(dsum, 8);
    float inv = 1.f / dsum;
    #pragma unroll
    for (int c = 0; c < 8; ++c) acc[c] += accn[c] * inv;
  }
  __shared__ float us[8][512];
  #pragma unroll
  for (int c = 0; c < 8; ++c) us[wid][hm*128 + c0 + c] = acc[c];
  __syncthreads();
  for (int i = threadIdx.x; i < 512; i += 512) {
    float v = 0.f;
    #pragma unroll
    for (int w = 0; w < 8; ++w) v += us[w][i];
    atomicAdd(&u[i], v);
  }
}

// ------------- final: g = (1/4N) sum_h u_h @ W2_h + b2; out = relu(g@Wo+bo) -
__global__ void k_final2(const float* __restrict__ u, const float* __restrict__ W2,
    const float* __restrict__ b2, const float* __restrict__ Wo,
    const float* __restrict__ bo, float* __restrict__ outp)
{
  __shared__ float g[128];
  int t = threadIdx.x;
  float acc = 0.f;
  for (int h = 0; h < 4; ++h)
    for (int k = 0; k < 128; ++k)
      acc += u[h*128 + k] * W2[(size_t)k*512 + h*128 + t];
  g[t] = acc * (1.f / (4.f * N_N)) + b2[t];
  __syncthreads();
  float o = 0.f;
  for (int c = 0; c < 128; ++c) o += g[c] * Wo[c*128 + t];
  o += bo[t];
  outp[t] = o > 0.f ? o : 0.f;
}

extern "C" void kernel_launch(void* const* d_in, const int* in_sizes, int n_in,
                              void* d_out, int out_size, void* d_ws, size_t ws_size,
                              hipStream_t stream) {
  const float* x    = (const float*)d_in[0];
  const void*  ei   = d_in[1];
  const float* Wp   = (const float*)d_in[2];
  const float* bp   = (const float*)d_in[3];
  const float* W1   = (const float*)d_in[4];
  const float* at_s1= (const float*)d_in[5];
  const float* at_d1= (const float*)d_in[6];
  const float* b1   = (const float*)d_in[7];
  const float* gamma= (const float*)d_in[8];
  const float* beta = (const float*)d_in[9];
  const float* W2   = (const float*)d_in[10];
  const float* at_s2= (const float*)d_in[11];
  const float* at_d2= (const float*)d_in[12];
  const float* b2   = (const float*)d_in[13];
  const float* Wo   = (const float*)d_in[14];
  const float* bo   = (const float*)d_in[15];

  const size_t NN = N_N;
  float* ws = (float*)d_ws;
  float*  h0f    = ws;                     // [N,128] f32: proj out; a1b aliases after
  ushort* a1b    = (ushort*)h0f;           // [N,128] bf16 (aliases h0f)
  ushort* h1b    = (ushort*)(ws + NN*128); // [N,128] bf16
  float*  sm     = ws + NN*128 + NN*64;
  int*    csr_col= (int*)sm;               // E_T
  int*    rptr   = csr_col + E_T;          // N+1
  uint*   stage  = (uint*)(rptr + N_N + 1);        // NBKT*BKT_CAP
  int*    bktpos = (int*)(stage + (size_t)NBKT*BKT_CAP); // NBKT*16
  int*    bktbase= bktpos + NBKT*16;       // NBKT
  float*  as1    = (float*)(bktbase + NBKT);
  float*  ad1    = as1 + NN*4;
  float*  as2    = ad1 + NN*4;
  float*  ad2    = as2 + NN*4;
  float*  vs2    = ad2 + NN*4;             // 512
  float*  vd2    = vs2 + 512;
  float*  u      = vd2 + 512;
  int*    modep  = (int*)(u + 512);

  size_t required = ((char*)(modep + 1)) - (char*)d_ws;
  if (ws_size < required) return;

  const int EB = (E_T + 255) / 256;
  const int NB4 = (N_N + 3) / 4;

  k_detect<<<1, 1, 0, stream>>>((const int*)ei, modep);
  k_zeroi<<<16, 256, 0, stream>>>(bktpos, NBKT*16);
  k_zeroi<<<2, 256, 0, stream>>>((int*)u, 512);
  k_bucket<<<EB, 256, 0, stream>>>(ei, modep, bktpos, stage);
  k_bktscan<<<1, 64, 0, stream>>>(bktpos, bktbase, rptr + N_N);
  k_bucket2<<<NBKT, 256, 0, stream>>>(bktpos, bktbase, stage, csr_col, rptr);

  k_proj<<<N_N/32, 256, 0, stream>>>(x, Wp, bp, h0f);
  k_gat_gemm128<<<N_N/32, 256, 0, stream>>>(h0f, W1, at_s1, at_d1, h1b, as1, ad1);
  k_fold2<<<1, 512, 0, stream>>>(W2, at_s2, at_d2, vs2, vd2);
  // a1b aliases h0f — safe: k_agg1 reads only h1b/as1/ad1; h0f dead after gemm128.
  k_agg1<<<NB4, 256, 0, stream>>>(rptr, csr_col, h1b, as1, ad1, b1, gamma, beta,
                                  vs2, vd2, a1b, as2, ad2);

  k_tail2<<<1024, 512, 0, stream>>>(rptr, csr_col, a1b, as2, ad2, u);
  k_final2<<<1, 128, 0, stream>>>(u, W2, b2, Wo, bo, (float*)d_out);
}

// Round 9
// 473.075 us; speedup vs baseline: 1.3495x; 1.3495x over previous
//
#include <hip/hip_runtime.h>

#define N_N 100000
#define N_E 1600000
#define E_T (N_E + N_N)

#define NBKT 196          // ceil(N_N / 512)
#define BKT_CAP 12288     // mean 8704, sigma ~93 -> 38 sigma headroom
#define CHUNK 4096
#define EPT 16            // edges per thread (256 threads * 16 = 4096)

typedef long long ll;
typedef unsigned int uint;
typedef unsigned short ushort;

__device__ __forceinline__ float lrelu(float v){ return v > 0.f ? v : 0.2f*v; }

__device__ __forceinline__ ushort f2bf(float f){
  uint u = __float_as_uint(f);
  uint r = (u + 0x7FFF + ((u >> 16) & 1)) >> 16;
  return (ushort)r;
}
__device__ __forceinline__ float bflo(uint p){ return __uint_as_float(p << 16); }
__device__ __forceinline__ float bfhi(uint p){ return __uint_as_float(p & 0xFFFF0000u); }

// Detect int64 vs int32 delivery of edge_index.
__global__ void k_detect(const int* __restrict__ ei32, int* __restrict__ mode) {
  int m = 1;
  for (int i = 1; i < 16; i += 2) if (ei32[i] != 0) m = 0;
  *mode = m;
}

__device__ __forceinline__ void load_edge(const void* eiv, int mode, int e, int& s, int& d) {
  if (e < N_E) {
    if (mode) {
      const ll* p = (const ll*)eiv;
      s = (int)p[e]; d = (int)p[N_E + e];
    } else {
      const int* p = (const int*)eiv;
      s = p[e]; d = p[N_E + e];
    }
  } else { s = d = e - N_E; }
}

__global__ void k_zeroi(int* __restrict__ p, int n) {
  for (int i = blockIdx.x*blockDim.x + threadIdx.x; i < n; i += gridDim.x*blockDim.x)
    p[i] = 0;
}

// ---------------- bucketed CSR build, block-aggregated atomics --------------
// Each block: 4096-edge chunk -> LDS hist over 196 buckets -> ONE global
// atomicAdd per (bucket, block) -> ranked writes into reserved ranges.
// Global atomics: 1.7M -> ~81K (no same-address serialization stall).
__global__ __launch_bounds__(256) void k_bucket_blk(const void* __restrict__ eiv,
    const int* __restrict__ modep, int* __restrict__ bktpos, uint* __restrict__ stage)
{
  __shared__ int cnt[NBKT], base[NBKT], lrank[NBKT];
  int m = *modep;
  int t = threadIdx.x;
  int e0 = blockIdx.x * CHUNK;
  int nedge = E_T - e0; if (nedge > CHUNK) nedge = CHUNK;
  for (int i = t; i < NBKT; i += 256) { cnt[i] = 0; lrank[i] = 0; }
  __syncthreads();
  uint pk[EPT]; int bb[EPT];
  #pragma unroll
  for (int i = 0; i < EPT; ++i) {
    int idx = t + i*256;
    if (idx < nedge) {
      int e = e0 + idx, s, d;
      load_edge(eiv, m, e, s, d);
      bb[i] = d >> 9;
      pk[i] = ((uint)(d & 511) << 17) | (uint)s;
      atomicAdd(&cnt[bb[i]], 1);
    } else bb[i] = -1;
  }
  __syncthreads();
  for (int i = t; i < NBKT; i += 256)
    if (cnt[i] > 0) base[i] = atomicAdd(&bktpos[i*16], cnt[i]);
  __syncthreads();
  #pragma unroll
  for (int i = 0; i < EPT; ++i) {
    if (bb[i] >= 0) {
      int b = bb[i];
      int r = atomicAdd(&lrank[b], 1);
      int off = base[b] + r;
      if (off < BKT_CAP) stage[(size_t)b*BKT_CAP + off] = pk[i];
    }
  }
}

// bucket base = exclusive prefix over bucket counts; also rptr[N] = E_T.
__global__ void k_bktscan(const int* __restrict__ bktpos, int* __restrict__ bktbase,
    int* __restrict__ rptrN)
{
  if (threadIdx.x == 0) {
    int run = 0;
    for (int b = 0; b < NBKT; ++b) { bktbase[b] = run; run += bktpos[b*16]; }
    *rptrN = run;
  }
}

// phase 2: one block per bucket. LDS hist over the bucket's 512 nodes,
// LDS ping-pong scan -> rptr, LDS-atomic ranks -> csr_col (~35KB write window).
__global__ __launch_bounds__(256) void k_bucket2(const int* __restrict__ bktpos,
    const int* __restrict__ bktbase, const uint* __restrict__ stage,
    int* __restrict__ csr_col, int* __restrict__ rptr)
{
  __shared__ int cntA[512], pA[512], pB[512], lpos[512];
  int b = blockIdx.x, t = threadIdx.x;
  int cnt = bktpos[b*16];
  if (cnt > BKT_CAP) cnt = BKT_CAP;
  int base = bktbase[b];
  const uint* st = stage + (size_t)b*BKT_CAP;
  for (int i = t; i < 512; i += 256) { cntA[i] = 0; lpos[i] = 0; }
  __syncthreads();
  for (int i = t; i < cnt; i += 256) atomicAdd(&cntA[st[i] >> 17], 1);
  __syncthreads();
  int* src = pA; int* dst = pB;
  for (int i = t; i < 512; i += 256) pA[i] = cntA[i];
  __syncthreads();
  for (int off = 1; off < 512; off <<= 1) {
    for (int i = t; i < 512; i += 256) {
      int v = src[i]; if (i >= off) v += src[i - off]; dst[i] = v;
    }
    __syncthreads();
    int* tmp = src; src = dst; dst = tmp;
  }
  // src = inclusive prefix; exclusive = src[i] - cntA[i]
  int nb0 = b*512;
  for (int i = t; i < 512; i += 256) {
    int node = nb0 + i;
    if (node < N_N) rptr[node] = base + src[i] - cntA[i];
  }
  __syncthreads();
  for (int i = t; i < cnt; i += 256) {
    uint pk = st[i];
    int dlow = (int)(pk >> 17), s = (int)(pk & 0x1FFFFu);
    int r = atomicAdd(&lpos[dlow], 1);
    csr_col[base + (src[dlow] - cntA[dlow]) + r] = s;
  }
}

// ---------------- proj: h0 = relu(x @ Wp + bp) ------------------------------
__global__ __launch_bounds__(256) void k_proj(const float* __restrict__ x,
    const float* __restrict__ Wp, const float* __restrict__ bp,
    float* __restrict__ h0)
{
  __shared__ float wl[64*128];
  __shared__ float xr[32*68];
  const int t = threadIdx.x;
  const int r0g = blockIdx.x * 32;
  for (int i = t; i < 64*128; i += 256) wl[i] = Wp[i];
  for (int i = t; i < 32*64; i += 256) {
    int r = i >> 6, k = i & 63;
    xr[r*68 + k] = x[(size_t)(r0g + r)*64 + k];
  }
  __syncthreads();
  const int tx = t & 31, ty = t >> 5;
  const int c0 = tx*4, r0 = ty*4;
  float acc[4][4] = {};
  for (int k = 0; k < 64; ++k) {
    float4 wv = *(const float4*)&wl[k*128 + c0];
    float x0 = xr[(r0+0)*68+k], x1 = xr[(r0+1)*68+k];
    float x2 = xr[(r0+2)*68+k], x3 = xr[(r0+3)*68+k];
    acc[0][0] += x0*wv.x; acc[0][1] += x0*wv.y; acc[0][2] += x0*wv.z; acc[0][3] += x0*wv.w;
    acc[1][0] += x1*wv.x; acc[1][1] += x1*wv.y; acc[1][2] += x1*wv.z; acc[1][3] += x1*wv.w;
    acc[2][0] += x2*wv.x; acc[2][1] += x2*wv.y; acc[2][2] += x2*wv.z; acc[2][3] += x2*wv.w;
    acc[3][0] += x3*wv.x; acc[3][1] += x3*wv.y; acc[3][2] += x3*wv.z; acc[3][3] += x3*wv.w;
  }
  float4 bb = *(const float4*)&bp[c0];
  for (int i = 0; i < 4; ++i) {
    int r = r0g + r0 + i;
    float4 o;
    o.x = fmaxf(acc[i][0] + bb.x, 0.f);
    o.y = fmaxf(acc[i][1] + bb.y, 0.f);
    o.z = fmaxf(acc[i][2] + bb.z, 0.f);
    o.w = fmaxf(acc[i][3] + bb.w, 0.f);
    *(float4*)&h0[(size_t)r*128 + c0] = o;
  }
}

// ------- layer-1 GEMM: H1(bf16) = h0 @ W1, fused alpha dots -----------------
__global__ __launch_bounds__(256) void k_gat_gemm128(const float* __restrict__ A,
    const float* __restrict__ W, const float* __restrict__ avs,
    const float* __restrict__ avd, ushort* __restrict__ Hb,
    float* __restrict__ as_o, float* __restrict__ ad_o)
{
  __shared__ float wl[64*128];
  __shared__ float xr[32*68];
  const int t = threadIdx.x;
  const int r0g = blockIdx.x * 32;
  const int tx = t & 31, ty = t >> 5;
  const int c0 = tx*4, r0 = ty*4;
  float acc[4][4] = {};
  for (int kc = 0; kc < 2; ++kc) {
    const int k0 = kc*64;
    if (kc) __syncthreads();
    for (int i = t; i < 64*128; i += 256) wl[i] = W[k0*128 + i];
    for (int i = t; i < 32*64; i += 256) {
      int r = i >> 6, k = i & 63;
      xr[r*68 + k] = A[(size_t)(r0g + r)*128 + k0 + k];
    }
    __syncthreads();
    for (int k = 0; k < 64; ++k) {
      float4 wv = *(const float4*)&wl[k*128 + c0];
      float x0 = xr[(r0+0)*68+k], x1 = xr[(r0+1)*68+k];
      float x2 = xr[(r0+2)*68+k], x3 = xr[(r0+3)*68+k];
      acc[0][0] += x0*wv.x; acc[0][1] += x0*wv.y; acc[0][2] += x0*wv.z; acc[0][3] += x0*wv.w;
      acc[1][0] += x1*wv.x; acc[1][1] += x1*wv.y; acc[1][2] += x1*wv.z; acc[1][3] += x1*wv.w;
      acc[2][0] += x2*wv.x; acc[2][1] += x2*wv.y; acc[2][2] += x2*wv.z; acc[2][3] += x2*wv.w;
      acc[3][0] += x3*wv.x; acc[3][1] += x3*wv.y; acc[3][2] += x3*wv.z; acc[3][3] += x3*wv.w;
    }
  }
  for (int i = 0; i < 4; ++i) {
    int r = r0g + r0 + i;
    uint p0 = (uint)f2bf(acc[i][0]) | ((uint)f2bf(acc[i][1]) << 16);
    uint p1 = (uint)f2bf(acc[i][2]) | ((uint)f2bf(acc[i][3]) << 16);
    *(uint2*)&Hb[(size_t)r*128 + c0] = make_uint2(p0, p1);
  }
  float4 sa = *(const float4*)&avs[c0];
  float4 da = *(const float4*)&avd[c0];
  for (int i = 0; i < 4; ++i) {
    float vs = acc[i][0]*sa.x + acc[i][1]*sa.y + acc[i][2]*sa.z + acc[i][3]*sa.w;
    float vd = acc[i][0]*da.x + acc[i][1]*da.y + acc[i][2]*da.z + acc[i][3]*da.w;
    vs += __shfl_xor(vs, 1); vs += __shfl_xor(vs, 2); vs += __shfl_xor(vs, 4);
    vd += __shfl_xor(vd, 1); vd += __shfl_xor(vd, 2); vd += __shfl_xor(vd, 4);
    if ((tx & 7) == 0) {
      int r = r0g + r0 + i;
      as_o[r*4 + (tx >> 3)] = vs;
      ad_o[r*4 + (tx >> 3)] = vd;
    }
  }
}

// ------------- fold W2 with att2 vectors ------------------------------------
__global__ void k_fold2(const float* __restrict__ W2,
    const float* __restrict__ att_s2, const float* __restrict__ att_d2,
    float* __restrict__ vs2, float* __restrict__ vd2)
{
  int t = threadIdx.x;            // 512 threads: k = t&127, h = t>>7
  int k = t & 127, hh = t >> 7;
  float accs = 0.f, accd = 0.f;
  for (int c = 0; c < 128; ++c) {
    float w = W2[(size_t)k*512 + hh*128 + c];
    accs += w * att_s2[hh*128 + c];
    accd += w * att_d2[hh*128 + c];
  }
  vs2[hh*128 + k] = accs;
  vd2[hh*128 + k] = accd;
}

// ------- fused layer-1 aggregate (wave per dst) + BN/ELU + layer-2 alpha ----
__global__ __launch_bounds__(256) void k_agg1(const int* __restrict__ rptr,
    const int* __restrict__ csr_col, const ushort* __restrict__ Hb,
    const float* __restrict__ as1, const float* __restrict__ ad1,
    const float* __restrict__ b1, const float* __restrict__ gamma,
    const float* __restrict__ beta, const float* __restrict__ vs2,
    const float* __restrict__ vd2, ushort* __restrict__ a1b,
    float* __restrict__ as2, float* __restrict__ ad2)
{
  int wid = threadIdx.x >> 6, l = threadIdx.x & 63;
  int n = blockIdx.x*4 + wid;
  if (n >= N_N) return;
  int jm = l & 15, hm = l >> 4;
  float adm = ad1[n*4 + hm];
  int beg = rptr[n], end = rptr[n+1];
  float accx = 0.f, accy = 0.f, den = 0.f;
  for (int e0 = beg; e0 < end; e0 += 16) {
    int ne = end - e0; if (ne > 16) ne = 16;
    int sM = 0; float wM = 0.f;
    if (jm < ne) {
      sM = csr_col[e0 + jm];
      wM = __expf(lrelu(as1[sM*4 + hm] + adm));
    }
    den += wM;
    for (int j = 0; j < ne; ++j) {
      int s = __shfl(sM, j);
      float w = __shfl(wM, (l & 48) + j);
      uint hv = *(const uint*)&Hb[(size_t)s*128 + 2*l];
      accx += w * bflo(hv);
      accy += w * bfhi(hv);
    }
  }
  den += __shfl_xor(den, 1); den += __shfl_xor(den, 2);
  den += __shfl_xor(den, 4); den += __shfl_xor(den, 8);
  float inv = 1.f / den;
  int c = 2*l;
  const float sc = 0.9999950000374997f;   // 1/sqrt(1+1e-5)
  float vx = (accx*inv + b1[c])   * (gamma[c]   * sc) + beta[c];
  float vy = (accy*inv + b1[c+1]) * (gamma[c+1] * sc) + beta[c+1];
  vx = vx > 0.f ? vx : __expf(vx) - 1.f;
  vy = vy > 0.f ? vy : __expf(vy) - 1.f;
  *(uint*)&a1b[(size_t)n*128 + c] = (uint)f2bf(vx) | ((uint)f2bf(vy) << 16);
  #pragma unroll
  for (int hh = 0; hh < 4; ++hh) {
    float2 wsv = *(const float2*)&vs2[hh*128 + c];
    float2 wdv = *(const float2*)&vd2[hh*128 + c];
    float ps = wsv.x*vx + wsv.y*vy;
    float pd = wdv.x*vx + wdv.y*vy;
    ps += __shfl_xor(ps, 1); ps += __shfl_xor(ps, 2); ps += __shfl_xor(ps, 4);
    ps += __shfl_xor(ps, 8); ps += __shfl_xor(ps, 16); ps += __shfl_xor(ps, 32);
    pd += __shfl_xor(pd, 1); pd += __shfl_xor(pd, 2); pd += __shfl_xor(pd, 4);
    pd += __shfl_xor(pd, 8); pd += __shfl_xor(pd, 16); pd += __shfl_xor(pd, 32);
    if (l == 0) { as2[n*4 + hh] = ps; ad2[n*4 + hh] = pd; }
  }
}

// ------- layer-2 tail: u[h,k] = sum_d sum_{s in N(d)} alpha*a1[s,k] ---------
__global__ __launch_bounds__(512) void k_tail2(const int* __restrict__ rptr,
    const int* __restrict__ csr_col, const ushort* __restrict__ a1b,
    const float* __restrict__ as2, const float* __restrict__ ad2,
    float* __restrict__ u)
{
  int wid = threadIdx.x >> 6, l = threadIdx.x & 63;
  int jm = l & 15, hm = l >> 4;
  int c0 = jm * 8;
  float acc[8] = {};
  for (int n = blockIdx.x*8 + wid; n < N_N; n += gridDim.x*8) {
    int beg = rptr[n], end = rptr[n+1];
    float adm = ad2[n*4 + hm];
    float accn[8] = {};
    float dsum = 0.f;
    for (int e0 = beg; e0 < end; e0 += 16) {
      int ne = end - e0; if (ne > 16) ne = 16;
      int sM = 0; float wM = 0.f;
      if (jm < ne) {
        sM = csr_col[e0 + jm];
        wM = __expf(lrelu(as2[sM*4 + hm] + adm));
      }
      dsum += wM;
      #pragma unroll 4
      for (int j = 0; j < ne; ++j) {
        int s = __shfl(sM, j);
        float w = __shfl(wM, (l & 48) + j);
        uint4 hv = *(const uint4*)&a1b[(size_t)s*128 + c0];
        accn[0] += w * bflo(hv.x); accn[1] += w * bfhi(hv.x);
        accn[2] += w * bflo(hv.y); accn[3] += w * bfhi(hv.y);
        accn[4] += w * bflo(hv.z); accn[5] += w * bfhi(hv.z);
        accn[6] += w * bflo(hv.w); accn[7] += w * bfhi(hv.w);
      }
    }
    dsum += __shfl_xor(dsum, 1); dsum += __shfl_xor(dsum, 2);
    dsum += __shfl_xor(dsum, 4); dsum += __shfl_xor(dsum, 8);
    float inv = 1.f / dsum;
    #pragma unroll
    for (int c = 0; c < 8; ++c) acc[c] += accn[c] * inv;
  }
  __shared__ float us[8][512];
  #pragma unroll
  for (int c = 0; c < 8; ++c) us[wid][hm*128 + c0 + c] = acc[c];
  __syncthreads();
  for (int i = threadIdx.x; i < 512; i += 512) {
    float v = 0.f;
    #pragma unroll
    for (int w = 0; w < 8; ++w) v += us[w][i];
    atomicAdd(&u[i], v);
  }
}

// ------------- final: g = (1/4N) sum_h u_h @ W2_h + b2; out = relu(g@Wo+bo) -
__global__ void k_final2(const float* __restrict__ u, const float* __restrict__ W2,
    const float* __restrict__ b2, const float* __restrict__ Wo,
    const float* __restrict__ bo, float* __restrict__ outp)
{
  __shared__ float g[128];
  int t = threadIdx.x;
  float acc = 0.f;
  for (int h = 0; h < 4; ++h)
    for (int k = 0; k < 128; ++k)
      acc += u[h*128 + k] * W2[(size_t)k*512 + h*128 + t];
  g[t] = acc * (1.f / (4.f * N_N)) + b2[t];
  __syncthreads();
  float o = 0.f;
  for (int c = 0; c < 128; ++c) o += g[c] * Wo[c*128 + t];
  o += bo[t];
  outp[t] = o > 0.f ? o : 0.f;
}

extern "C" void kernel_launch(void* const* d_in, const int* in_sizes, int n_in,
                              void* d_out, int out_size, void* d_ws, size_t ws_size,
                              hipStream_t stream) {
  const float* x    = (const float*)d_in[0];
  const void*  ei   = d_in[1];
  const float* Wp   = (const float*)d_in[2];
  const float* bp   = (const float*)d_in[3];
  const float* W1   = (const float*)d_in[4];
  const float* at_s1= (const float*)d_in[5];
  const float* at_d1= (const float*)d_in[6];
  const float* b1   = (const float*)d_in[7];
  const float* gamma= (const float*)d_in[8];
  const float* beta = (const float*)d_in[9];
  const float* W2   = (const float*)d_in[10];
  const float* at_s2= (const float*)d_in[11];
  const float* at_d2= (const float*)d_in[12];
  const float* b2   = (const float*)d_in[13];
  const float* Wo   = (const float*)d_in[14];
  const float* bo   = (const float*)d_in[15];

  const size_t NN = N_N;
  float* ws = (float*)d_ws;
  float*  h0f    = ws;                     // [N,128] f32: proj out; a1b aliases after
  ushort* a1b    = (ushort*)h0f;           // [N,128] bf16 (aliases h0f)
  ushort* h1b    = (ushort*)(ws + NN*128); // [N,128] bf16
  float*  sm     = ws + NN*128 + NN*64;
  int*    csr_col= (int*)sm;               // E_T
  int*    rptr   = csr_col + E_T;          // N+1
  uint*   stage  = (uint*)(rptr + N_N + 1);        // NBKT*BKT_CAP
  int*    bktpos = (int*)(stage + (size_t)NBKT*BKT_CAP); // NBKT*16
  int*    bktbase= bktpos + NBKT*16;       // NBKT
  float*  as1    = (float*)(bktbase + NBKT);
  float*  ad1    = as1 + NN*4;
  float*  as2    = ad1 + NN*4;
  float*  ad2    = as2 + NN*4;
  float*  vs2    = ad2 + NN*4;             // 512
  float*  vd2    = vs2 + 512;
  float*  u      = vd2 + 512;
  int*    modep  = (int*)(u + 512);

  size_t required = ((char*)(modep + 1)) - (char*)d_ws;
  if (ws_size < required) return;

  const int NB4 = (N_N + 3) / 4;
  const int NCHUNK = (E_T + CHUNK - 1) / CHUNK;   // 416

  k_detect<<<1, 1, 0, stream>>>((const int*)ei, modep);
  k_zeroi<<<16, 256, 0, stream>>>(bktpos, NBKT*16);
  k_zeroi<<<2, 256, 0, stream>>>((int*)u, 512);
  k_bucket_blk<<<NCHUNK, 256, 0, stream>>>(ei, modep, bktpos, stage);
  k_bktscan<<<1, 64, 0, stream>>>(bktpos, bktbase, rptr + N_N);
  k_bucket2<<<NBKT, 256, 0, stream>>>(bktpos, bktbase, stage, csr_col, rptr);

  k_proj<<<N_N/32, 256, 0, stream>>>(x, Wp, bp, h0f);
  k_gat_gemm128<<<N_N/32, 256, 0, stream>>>(h0f, W1, at_s1, at_d1, h1b, as1, ad1);
  k_fold2<<<1, 512, 0, stream>>>(W2, at_s2, at_d2, vs2, vd2);
  // a1b aliases h0f — safe: k_agg1 reads only h1b/as1/ad1; h0f dead after gemm128.
  k_agg1<<<NB4, 256, 0, stream>>>(rptr, csr_col, h1b, as1, ad1, b1, gamma, beta,
                                  vs2, vd2, a1b, as2, ad2);

  k_tail2<<<1024, 512, 0, stream>>>(rptr, csr_col, a1b, as2, ad2, u);
  k_final2<<<1, 128, 0, stream>>>(u, W2, b2, Wo, bo, (float*)d_out);
}

// Round 11
// 456.389 us; speedup vs baseline: 1.3989x; 1.0366x over previous
//
#include <hip/hip_runtime.h>

#define N_N 100000
#define N_E 1600000
#define E_T (N_E + N_N)

#define NBKT 196          // ceil(N_N / 512)
#define BKT_CAP 12288     // mean 8704, sigma ~93 -> 38 sigma headroom
#define CHUNK 4096
#define EPT 16            // edges per thread (256 threads * 16 = 4096)

typedef long long ll;
typedef unsigned int uint;
typedef unsigned short ushort;
typedef unsigned char uchar;
typedef float floatx2 __attribute__((ext_vector_type(2)));

__device__ __forceinline__ float lrelu(float v){ return v > 0.f ? v : 0.2f*v; }

// fp8 e4m3 HW converts (gfx940+; OCP on gfx950 — encode & decode both on-device)
__device__ __forceinline__ uint pk_fp8_quad(float a, float b, float c, float d){
  int w = __builtin_amdgcn_cvt_pk_fp8_f32(a, b, 0, false);
  w = __builtin_amdgcn_cvt_pk_fp8_f32(c, d, w, true);
  return (uint)w;
}
// wsel must be a literal: instantiate both variants, select at runtime.
__device__ __forceinline__ floatx2 unpk_fp8(uint v, int wsel){
  floatx2 lo = __builtin_amdgcn_cvt_pk_f32_fp8((int)v, false);
  floatx2 hi = __builtin_amdgcn_cvt_pk_f32_fp8((int)v, true);
  return wsel ? hi : lo;
}

// Detect int64 vs int32 delivery of edge_index.
__global__ void k_detect(const int* __restrict__ ei32, int* __restrict__ mode) {
  int m = 1;
  for (int i = 1; i < 16; i += 2) if (ei32[i] != 0) m = 0;
  *mode = m;
}

__device__ __forceinline__ void load_edge(const void* eiv, int mode, int e, int& s, int& d) {
  if (e < N_E) {
    if (mode) {
      const ll* p = (const ll*)eiv;
      s = (int)p[e]; d = (int)p[N_E + e];
    } else {
      const int* p = (const int*)eiv;
      s = p[e]; d = p[N_E + e];
    }
  } else { s = d = e - N_E; }
}

__global__ void k_zeroi(int* __restrict__ p, int n) {
  for (int i = blockIdx.x*blockDim.x + threadIdx.x; i < n; i += gridDim.x*blockDim.x)
    p[i] = 0;
}

// ---------------- bucketed CSR build, block-aggregated atomics --------------
__global__ __launch_bounds__(256) void k_bucket_blk(const void* __restrict__ eiv,
    const int* __restrict__ modep, int* __restrict__ bktpos, uint* __restrict__ stage)
{
  __shared__ int cnt[NBKT], base[NBKT], lrank[NBKT];
  int m = *modep;
  int t = threadIdx.x;
  int e0 = blockIdx.x * CHUNK;
  int nedge = E_T - e0; if (nedge > CHUNK) nedge = CHUNK;
  for (int i = t; i < NBKT; i += 256) { cnt[i] = 0; lrank[i] = 0; }
  __syncthreads();
  uint pk[EPT]; int bb[EPT];
  #pragma unroll
  for (int i = 0; i < EPT; ++i) {
    int idx = t + i*256;
    if (idx < nedge) {
      int e = e0 + idx, s, d;
      load_edge(eiv, m, e, s, d);
      bb[i] = d >> 9;
      pk[i] = ((uint)(d & 511) << 17) | (uint)s;
      atomicAdd(&cnt[bb[i]], 1);
    } else bb[i] = -1;
  }
  __syncthreads();
  for (int i = t; i < NBKT; i += 256)
    if (cnt[i] > 0) base[i] = atomicAdd(&bktpos[i*16], cnt[i]);
  __syncthreads();
  #pragma unroll
  for (int i = 0; i < EPT; ++i) {
    if (bb[i] >= 0) {
      int b = bb[i];
      int r = atomicAdd(&lrank[b], 1);
      int off = base[b] + r;
      if (off < BKT_CAP) stage[(size_t)b*BKT_CAP + off] = pk[i];
    }
  }
}

__global__ void k_bktscan(const int* __restrict__ bktpos, int* __restrict__ bktbase,
    int* __restrict__ rptrN)
{
  if (threadIdx.x == 0) {
    int run = 0;
    for (int b = 0; b < NBKT; ++b) { bktbase[b] = run; run += bktpos[b*16]; }
    *rptrN = run;
  }
}

__global__ __launch_bounds__(256) void k_bucket2(const int* __restrict__ bktpos,
    const int* __restrict__ bktbase, const uint* __restrict__ stage,
    int* __restrict__ csr_col, int* __restrict__ rptr)
{
  __shared__ int cntA[512], pA[512], pB[512], lpos[512];
  int b = blockIdx.x, t = threadIdx.x;
  int cnt = bktpos[b*16];
  if (cnt > BKT_CAP) cnt = BKT_CAP;
  int base = bktbase[b];
  const uint* st = stage + (size_t)b*BKT_CAP;
  for (int i = t; i < 512; i += 256) { cntA[i] = 0; lpos[i] = 0; }
  __syncthreads();
  for (int i = t; i < cnt; i += 256) atomicAdd(&cntA[st[i] >> 17], 1);
  __syncthreads();
  int* src = pA; int* dst = pB;
  for (int i = t; i < 512; i += 256) pA[i] = cntA[i];
  __syncthreads();
  for (int off = 1; off < 512; off <<= 1) {
    for (int i = t; i < 512; i += 256) {
      int v = src[i]; if (i >= off) v += src[i - off]; dst[i] = v;
    }
    __syncthreads();
    int* tmp = src; src = dst; dst = tmp;
  }
  int nb0 = b*512;
  for (int i = t; i < 512; i += 256) {
    int node = nb0 + i;
    if (node < N_N) rptr[node] = base + src[i] - cntA[i];
  }
  __syncthreads();
  for (int i = t; i < cnt; i += 256) {
    uint pk = st[i];
    int dlow = (int)(pk >> 17), s = (int)(pk & 0x1FFFFu);
    int r = atomicAdd(&lpos[dlow], 1);
    csr_col[base + (src[dlow] - cntA[dlow]) + r] = s;
  }
}

// ---- fused proj + layer-1 GEMM: h0 = relu(x@Wp+bp) in LDS; H1 = h0@W1 ------
// H1 stored fp8 e4m3; fused alpha dots from f32 accumulators.
__global__ __launch_bounds__(256) void k_fused12(const float* __restrict__ x,
    const float* __restrict__ Wp, const float* __restrict__ bp,
    const float* __restrict__ W1, const float* __restrict__ avs,
    const float* __restrict__ avd, uchar* __restrict__ Hb8,
    float* __restrict__ as_o, float* __restrict__ ad_o)
{
  __shared__ float wl[64*128];
  __shared__ float h0s[32*132];
  __shared__ float xr[32*68];
  const int t = threadIdx.x;
  const int r0g = blockIdx.x * 32;
  const int tx = t & 31, ty = t >> 5;
  const int c0 = tx*4, r0 = ty*4;
  // phase 1: h0 tile
  for (int i = t; i < 64*128; i += 256) wl[i] = Wp[i];
  for (int i = t; i < 32*64; i += 256) {
    int r = i >> 6, k = i & 63;
    xr[r*68 + k] = x[(size_t)(r0g + r)*64 + k];
  }
  __syncthreads();
  {
    float acc[4][4] = {};
    for (int k = 0; k < 64; ++k) {
      float4 wv = *(const float4*)&wl[k*128 + c0];
      float x0 = xr[(r0+0)*68+k], x1 = xr[(r0+1)*68+k];
      float x2 = xr[(r0+2)*68+k], x3 = xr[(r0+3)*68+k];
      acc[0][0] += x0*wv.x; acc[0][1] += x0*wv.y; acc[0][2] += x0*wv.z; acc[0][3] += x0*wv.w;
      acc[1][0] += x1*wv.x; acc[1][1] += x1*wv.y; acc[1][2] += x1*wv.z; acc[1][3] += x1*wv.w;
      acc[2][0] += x2*wv.x; acc[2][1] += x2*wv.y; acc[2][2] += x2*wv.z; acc[2][3] += x2*wv.w;
      acc[3][0] += x3*wv.x; acc[3][1] += x3*wv.y; acc[3][2] += x3*wv.z; acc[3][3] += x3*wv.w;
    }
    float4 bb = *(const float4*)&bp[c0];
    for (int i = 0; i < 4; ++i) {
      h0s[(r0+i)*132 + c0    ] = fmaxf(acc[i][0] + bb.x, 0.f);
      h0s[(r0+i)*132 + c0 + 1] = fmaxf(acc[i][1] + bb.y, 0.f);
      h0s[(r0+i)*132 + c0 + 2] = fmaxf(acc[i][2] + bb.z, 0.f);
      h0s[(r0+i)*132 + c0 + 3] = fmaxf(acc[i][3] + bb.w, 0.f);
    }
  }
  // phase 2: H1 = h0s @ W1
  float acc[4][4] = {};
  for (int kc = 0; kc < 2; ++kc) {
    const int k0 = kc*64;
    __syncthreads();
    for (int i = t; i < 64*128; i += 256) wl[i] = W1[k0*128 + i];
    __syncthreads();
    for (int k = 0; k < 64; ++k) {
      float4 wv = *(const float4*)&wl[k*128 + c0];
      int kk = k0 + k;
      float x0 = h0s[(r0+0)*132+kk], x1 = h0s[(r0+1)*132+kk];
      float x2 = h0s[(r0+2)*132+kk], x3 = h0s[(r0+3)*132+kk];
      acc[0][0] += x0*wv.x; acc[0][1] += x0*wv.y; acc[0][2] += x0*wv.z; acc[0][3] += x0*wv.w;
      acc[1][0] += x1*wv.x; acc[1][1] += x1*wv.y; acc[1][2] += x1*wv.z; acc[1][3] += x1*wv.w;
      acc[2][0] += x2*wv.x; acc[2][1] += x2*wv.y; acc[2][2] += x2*wv.z; acc[2][3] += x2*wv.w;
      acc[3][0] += x3*wv.x; acc[3][1] += x3*wv.y; acc[3][2] += x3*wv.z; acc[3][3] += x3*wv.w;
    }
  }
  for (int i = 0; i < 4; ++i) {
    int r = r0g + r0 + i;
    ((uint*)&Hb8[(size_t)r*128])[tx] =
      pk_fp8_quad(acc[i][0], acc[i][1], acc[i][2], acc[i][3]);
  }
  float4 sa = *(const float4*)&avs[c0];
  float4 da = *(const float4*)&avd[c0];
  for (int i = 0; i < 4; ++i) {
    float vs = acc[i][0]*sa.x + acc[i][1]*sa.y + acc[i][2]*sa.z + acc[i][3]*sa.w;
    float vd = acc[i][0]*da.x + acc[i][1]*da.y + acc[i][2]*da.z + acc[i][3]*da.w;
    vs += __shfl_xor(vs, 1); vs += __shfl_xor(vs, 2); vs += __shfl_xor(vs, 4);
    vd += __shfl_xor(vd, 1); vd += __shfl_xor(vd, 2); vd += __shfl_xor(vd, 4);
    if ((tx & 7) == 0) {
      int r = r0g + r0 + i;
      as_o[r*4 + (tx >> 3)] = vs;
      ad_o[r*4 + (tx >> 3)] = vd;
    }
  }
}

// ------------- fold W2 with att2 vectors ------------------------------------
__global__ void k_fold2(const float* __restrict__ W2,
    const float* __restrict__ att_s2, const float* __restrict__ att_d2,
    float* __restrict__ vs2, float* __restrict__ vd2)
{
  int t = threadIdx.x;            // 512 threads: k = t&127, h = t>>7
  int k = t & 127, hh = t >> 7;
  float accs = 0.f, accd = 0.f;
  for (int c = 0; c < 128; ++c) {
    float w = W2[(size_t)k*512 + hh*128 + c];
    accs += w * att_s2[hh*128 + c];
    accd += w * att_d2[hh*128 + c];
  }
  vs2[hh*128 + k] = accs;
  vd2[hh*128 + k] = accd;
}

// ------- fused layer-1 aggregate (wave per dst) + BN/ELU + layer-2 alpha ----
// Hb fp8: lanes 2k,2k+1 share one uint (coalesced 128B/row); a1 out fp8.
__global__ __launch_bounds__(256) void k_agg1(const int* __restrict__ rptr,
    const int* __restrict__ csr_col, const uchar* __restrict__ Hb8,
    const float* __restrict__ as1, const float* __restrict__ ad1,
    const float* __restrict__ b1, const float* __restrict__ gamma,
    const float* __restrict__ beta, const float* __restrict__ vs2,
    const float* __restrict__ vd2, uchar* __restrict__ a1f8,
    float* __restrict__ as2, float* __restrict__ ad2)
{
  int wid = threadIdx.x >> 6, l = threadIdx.x & 63;
  int n = blockIdx.x*4 + wid;
  if (n >= N_N) return;
  int jm = l & 15, hm = l >> 4;
  const int wsel = l & 1, widx = l >> 1;
  float adm = ad1[n*4 + hm];
  int beg = rptr[n], end = rptr[n+1];
  float accx = 0.f, accy = 0.f, den = 0.f;
  for (int e0 = beg; e0 < end; e0 += 16) {
    int ne = end - e0; if (ne > 16) ne = 16;
    int sM = 0; float wM = 0.f;
    if (jm < ne) {
      sM = csr_col[e0 + jm];
      wM = __expf(lrelu(as1[sM*4 + hm] + adm));
    }
    den += wM;
    for (int j = 0; j < ne; ++j) {
      int s = __shfl(sM, j);
      float w = __shfl(wM, (l & 48) + j);
      uint hv = ((const uint*)&Hb8[(size_t)s*128])[widx];
      floatx2 dv = unpk_fp8(hv, wsel);
      accx += w * dv.x;
      accy += w * dv.y;
    }
  }
  den += __shfl_xor(den, 1); den += __shfl_xor(den, 2);
  den += __shfl_xor(den, 4); den += __shfl_xor(den, 8);
  float inv = 1.f / den;
  int c = 2*l;
  const float sc = 0.9999950000374997f;   // 1/sqrt(1+1e-5)
  float vx = (accx*inv + b1[c])   * (gamma[c]   * sc) + beta[c];
  float vy = (accy*inv + b1[c+1]) * (gamma[c+1] * sc) + beta[c+1];
  vx = vx > 0.f ? vx : __expf(vx) - 1.f;
  vy = vy > 0.f ? vy : __expf(vy) - 1.f;
  int pk = __builtin_amdgcn_cvt_pk_fp8_f32(vx, vy, 0, false);
  *(ushort*)&a1f8[(size_t)n*128 + c] = (ushort)pk;
  #pragma unroll
  for (int hh = 0; hh < 4; ++hh) {
    float2 wsv = *(const float2*)&vs2[hh*128 + c];
    float2 wdv = *(const float2*)&vd2[hh*128 + c];
    float ps = wsv.x*vx + wsv.y*vy;
    float pd = wdv.x*vx + wdv.y*vy;
    ps += __shfl_xor(ps, 1); ps += __shfl_xor(ps, 2); ps += __shfl_xor(ps, 4);
    ps += __shfl_xor(ps, 8); ps += __shfl_xor(ps, 16); ps += __shfl_xor(ps, 32);
    pd += __shfl_xor(pd, 1); pd += __shfl_xor(pd, 2); pd += __shfl_xor(pd, 4);
    pd += __shfl_xor(pd, 8); pd += __shfl_xor(pd, 16); pd += __shfl_xor(pd, 32);
    if (l == 0) { as2[n*4 + hh] = ps; ad2[n*4 + hh] = pd; }
  }
}

// ------- layer-2 tail: u[h,k] = sum_d sum_{s in N(d)} alpha*a1[s,k] ---------
// a1 fp8: lane reads uint2 = 8 fp8 cols; 16-lane group covers the 128B row.
__global__ __launch_bounds__(512) void k_tail2(const int* __restrict__ rptr,
    const int* __restrict__ csr_col, const uchar* __restrict__ a1f8,
    const float* __restrict__ as2, const float* __restrict__ ad2,
    float* __restrict__ u)
{
  int wid = threadIdx.x >> 6, l = threadIdx.x & 63;
  int jm = l & 15, hm = l >> 4;
  int c0 = jm * 8;
  float acc[8] = {};
  for (int n = blockIdx.x*8 + wid; n < N_N; n += gridDim.x*8) {
    int beg = rptr[n], end = rptr[n+1];
    float adm = ad2[n*4 + hm];
    float accn[8] = {};
    float dsum = 0.f;
    for (int e0 = beg; e0 < end; e0 += 16) {
      int ne = end - e0; if (ne > 16) ne = 16;
      int sM = 0; float wM = 0.f;
      if (jm < ne) {
        sM = csr_col[e0 + jm];
        wM = __expf(lrelu(as2[sM*4 + hm] + adm));
      }
      dsum += wM;
      #pragma unroll 4
      for (int j = 0; j < ne; ++j) {
        int s = __shfl(sM, j);
        float w = __shfl(wM, (l & 48) + j);
        uint2 hv = *(const uint2*)&a1f8[(size_t)s*128 + c0];
        floatx2 d0 = __builtin_amdgcn_cvt_pk_f32_fp8((int)hv.x, false);
        floatx2 d1 = __builtin_amdgcn_cvt_pk_f32_fp8((int)hv.x, true);
        floatx2 d2 = __builtin_amdgcn_cvt_pk_f32_fp8((int)hv.y, false);
        floatx2 d3 = __builtin_amdgcn_cvt_pk_f32_fp8((int)hv.y, true);
        accn[0] += w * d0.x; accn[1] += w * d0.y;
        accn[2] += w * d1.x; accn[3] += w * d1.y;
        accn[4] += w * d2.x; accn[5] += w * d2.y;
        accn[6] += w * d3.x; accn[7] += w * d3.y;
      }
    }
    dsum += __shfl_xor(dsum, 1); dsum += __shfl_xor(dsum, 2);
    dsum += __shfl_xor(dsum, 4); dsum += __shfl_xor(dsum, 8);
    float inv = 1.f / dsum;
    #pragma unroll
    for (int c = 0; c < 8; ++c) acc[c] += accn[c] * inv;
  }
  __shared__ float us[8][512];
  #pragma unroll
  for (int c = 0; c < 8; ++c) us[wid][hm*128 + c0 + c] = acc[c];
  __syncthreads();
  for (int i = threadIdx.x; i < 512; i += 512) {
    float v = 0.f;
    #pragma unroll
    for (int w = 0; w < 8; ++w) v += us[w][i];
    atomicAdd(&u[i], v);
  }
}

// ------------- final: g = (1/4N) sum_h u_h @ W2_h + b2; out = relu(g@Wo+bo) -
__global__ void k_final2(const float* __restrict__ u, const float* __restrict__ W2,
    const float* __restrict__ b2, const float* __restrict__ Wo,
    const float* __restrict__ bo, float* __restrict__ outp)
{
  __shared__ float g[128];
  int t = threadIdx.x;
  float acc = 0.f;
  for (int h = 0; h < 4; ++h)
    for (int k = 0; k < 128; ++k)
      acc += u[h*128 + k] * W2[(size_t)k*512 + h*128 + t];
  g[t] = acc * (1.f / (4.f * N_N)) + b2[t];
  __syncthreads();
  float o = 0.f;
  for (int c = 0; c < 128; ++c) o += g[c] * Wo[c*128 + t];
  o += bo[t];
  outp[t] = o > 0.f ? o : 0.f;
}

extern "C" void kernel_launch(void* const* d_in, const int* in_sizes, int n_in,
                              void* d_out, int out_size, void* d_ws, size_t ws_size,
                              hipStream_t stream) {
  const float* x    = (const float*)d_in[0];
  const void*  ei   = d_in[1];
  const float* Wp   = (const float*)d_in[2];
  const float* bp   = (const float*)d_in[3];
  const float* W1   = (const float*)d_in[4];
  const float* at_s1= (const float*)d_in[5];
  const float* at_d1= (const float*)d_in[6];
  const float* b1   = (const float*)d_in[7];
  const float* gamma= (const float*)d_in[8];
  const float* beta = (const float*)d_in[9];
  const float* W2   = (const float*)d_in[10];
  const float* at_s2= (const float*)d_in[11];
  const float* at_d2= (const float*)d_in[12];
  const float* b2   = (const float*)d_in[13];
  const float* Wo   = (const float*)d_in[14];
  const float* bo   = (const float*)d_in[15];

  const size_t NN = N_N;
  uchar* hb8   = (uchar*)d_ws;                 // [N,128] fp8
  uchar* a1f8  = hb8 + NN*128;                 // [N,128] fp8
  int*   csr_col = (int*)(a1f8 + NN*128);      // E_T
  int*   rptr    = csr_col + E_T;              // N+1
  uint*  stage   = (uint*)(rptr + N_N + 1);    // NBKT*BKT_CAP
  int*   bktpos  = (int*)(stage + (size_t)NBKT*BKT_CAP); // NBKT*16
  int*   bktbase = bktpos + NBKT*16;           // NBKT
  float* as1     = (float*)(bktbase + NBKT);
  float* ad1     = as1 + NN*4;
  float* as2     = ad1 + NN*4;
  float* ad2     = as2 + NN*4;
  float* vs2     = ad2 + NN*4;                 // 512
  float* vd2     = vs2 + 512;
  float* u       = vd2 + 512;
  int*   modep   = (int*)(u + 512);

  size_t required = ((char*)(modep + 1)) - (char*)d_ws;
  if (ws_size < required) return;

  const int NB4 = (N_N + 3) / 4;
  const int NCHUNK = (E_T + CHUNK - 1) / CHUNK;   // 416

  k_detect<<<1, 1, 0, stream>>>((const int*)ei, modep);
  k_zeroi<<<16, 256, 0, stream>>>(bktpos, NBKT*16);
  k_zeroi<<<2, 256, 0, stream>>>((int*)u, 512);
  k_bucket_blk<<<NCHUNK, 256, 0, stream>>>(ei, modep, bktpos, stage);
  k_bktscan<<<1, 64, 0, stream>>>(bktpos, bktbase, rptr + N_N);
  k_bucket2<<<NBKT, 256, 0, stream>>>(bktpos, bktbase, stage, csr_col, rptr);

  k_fused12<<<N_N/32, 256, 0, stream>>>(x, Wp, bp, W1, at_s1, at_d1, hb8, as1, ad1);
  k_fold2<<<1, 512, 0, stream>>>(W2, at_s2, at_d2, vs2, vd2);
  k_agg1<<<NB4, 256, 0, stream>>>(rptr, csr_col, hb8, as1, ad1, b1, gamma, beta,
                                  vs2, vd2, a1f8, as2, ad2);

  k_tail2<<<1024, 512, 0, stream>>>(rptr, csr_col, a1f8, as2, ad2, u);
  k_final2<<<1, 128, 0, stream>>>(u, W2, b2, Wo, bo, (float*)d_out);
}